// Round 9
// baseline (237.882 us; speedup 1.0000x reference)
//
#include <hip/hip_runtime.h>
#include <hip/hip_bf16.h>

#define NB 16
#define NP 1024
#define NS 32
#define NC 76
#define XSTR 104   // xb k-stride (shorts): 96 used + 8 pad; 16B-multiple
#define HSTR 136   // hb k-stride (shorts): 128 used + 8 pad; 16B-multiple
#define TPB 8      // tiles per block; tile = 4 points; grid = 512 = 2 blocks/CU

typedef __attribute__((ext_vector_type(8))) short bf16x8;
typedef __attribute__((ext_vector_type(4))) float f32x4;

__device__ inline short f2bf(float f) {
  unsigned u = __builtin_bit_cast(unsigned, f);
  u = u + 0x7fffu + ((u >> 16) & 1u);   // RNE
  return (short)(u >> 16);
}
__device__ inline unsigned cvt_pk_bf16(float lo, float hi) {
  unsigned r;
  asm("v_cvt_pk_bf16_f32 %0, %1, %2" : "=v"(r) : "v"(lo), "v"(hi));
  return r;
}
// Swizzle: fold col bits 4..6 (uniform per 16-col fragment window -> read
// bank-pattern untouched) into addr bits 3..5 (16B-granular). Bijective.
__device__ inline int swzx(int col, int k) {
  return (col * XSTR + k) ^ (((col >> 4) & 7) << 3);
}
__device__ inline int swzh(int col, int k) {
  return (col * HSTR + k) ^ (((col >> 4) & 7) << 3);
}
// max across 16-lane groups via DPP butterfly (VALU pipe, no LDS)
__device__ inline float dpp_max16(float v) {
  int x;
  x = __builtin_amdgcn_update_dpp(0, __builtin_bit_cast(int, v), 0xB1, 0xf, 0xf, true);
  v = fmaxf(v, __builtin_bit_cast(float, x));
  x = __builtin_amdgcn_update_dpp(0, __builtin_bit_cast(int, v), 0x4E, 0xf, 0xf, true);
  v = fmaxf(v, __builtin_bit_cast(float, x));
  x = __builtin_amdgcn_update_dpp(0, __builtin_bit_cast(int, v), 0x141, 0xf, 0xf, true);
  v = fmaxf(v, __builtin_bit_cast(float, x));
  x = __builtin_amdgcn_update_dpp(0, __builtin_bit_cast(int, v), 0x140, 0xf, 0xf, true);
  v = fmaxf(v, __builtin_bit_cast(float, x));
  return v;
}

// ---------------- single fused kernel: frames + MLP + pool ----------------
// 512 threads = 8 waves (4 row-stripes x 2 col-halves). Tile = 4 points =
// 128 cols. SINGLE xb / hb buffers (61.4 KB) -> 2 blocks/CU = 16 waves/CU.
// Loop: L1(t)+h1store | bar | fill(t+1) overlaps L2(t)+pool | bar.
// Frames (azi mean + Gram-Schmidt) in-register inside fill (32-lane shuffle
// reduce per point); azi_u written to out ch 0..2 there.
// xb [col][k]: 0..63 feats(ch12..75); 64..66 R*rel; 67..69 R*o_n; 70..72
// dir_dif; 73 = 1.0 (bias row, static); 74..95 = 0 (static).
__global__ __launch_bounds__(512, 4)
void mlp_kernel(const float* __restrict__ inp, const float* __restrict__ w1g,
                const float* __restrict__ b1g, const float* __restrict__ w2g,
                const float* __restrict__ b2g, const float* __restrict__ normal,
                float* __restrict__ out) {
  __shared__ short xb[128 * XSTR];   // 26,624 B
  __shared__ short hb[128 * HSTR];   // 34,816 B
  const int tid = threadIdx.x;
  const int lane = tid & 63;
  const int wv = tid >> 6;
  const int wr = wv >> 1;           // row-stripe 0..3 -> rows 32*wr..
  const int wc = wv & 1;            // col-half 0..1 -> cols 64*wc..
  const int l15 = lane & 15;
  const int l4 = lane >> 4;         // 0..3

  const int tile0 = blockIdx.x * TPB;

  // fill-phase thread map (feats)
  const int s4  = tid & 7;          // s quad
  const int flp = (tid >> 3) & 3;   // point within tile
  const int chq = tid >> 5;         // channel quad 0..15 -> k = 4*chq
  const int colb = flp*32 + 4*s4;

  // ----- weight fragments (rows 32*wr+16*mf+l15); b1 folded at kk=73 -----
  bf16x8 w1f[2][3];
#pragma unroll
  for (int mf = 0; mf < 2; ++mf)
#pragma unroll
    for (int ks = 0; ks < 3; ++ks) {
      bf16x8 a;
#pragma unroll
      for (int j = 0; j < 8; ++j) {
        int row = 32*wr + 16*mf + l15;
        int kk = 32*ks + 8*l4 + j;
        float v = 0.f;
        if (kk < 73) {
          int c = (kk < 64) ? (kk + 3) : ((kk < 67) ? (kk - 64) : kk);
          v = w1g[row*73 + c];
        } else if (kk == 73) {
          v = b1g[row];
        }
        a[j] = f2bf(v);
      }
      w1f[mf][ks] = a;
    }
  bf16x8 w2f[2][4];
#pragma unroll
  for (int mf = 0; mf < 2; ++mf)
#pragma unroll
    for (int ks = 0; ks < 4; ++ks) {
      bf16x8 a;
#pragma unroll
      for (int j = 0; j < 8; ++j) {
        int row = 32*wr + 16*mf + l15;
        int kk = 32*ks + 8*l4 + j;
        a[j] = f2bf(w2g[row*128 + kk]);
      }
      w2f[mf][ks] = a;
    }
  float bias2[2][4];
#pragma unroll
  for (int mf = 0; mf < 2; ++mf)
#pragma unroll
    for (int r = 0; r < 4; ++r)
      bias2[mf][r] = b2g[32*wr + 16*mf + 4*l4 + r];

  // static pad region of xb: k=73 -> 1.0, (73,96) -> 0
  for (int i = tid; i < 128*23; i += 512) {
    int col = i / 23;
    int k = 73 + (i - col*23);
    xb[swzx(col, k)] = (k == 73) ? (short)0x3F80 : (short)0;
  }

  // ----- feat staging registers (next tile); dead before frames block -----
  float4 sf0, sf1, sf2, sf3;
  auto stage = [&](int it2) {
    const int tile = tile0 + it2;
    const int bb = tile >> 8;
    const int pb = (tile & 255) * 4;
    const float* base = inp + ((size_t)((bb*NC + 12 + 4*chq)*NP) + pb + flp)*NS + 4*s4;
    sf0 = *(const float4*)(base + 0*(size_t)NP*NS);
    sf1 = *(const float4*)(base + 1*(size_t)NP*NS);
    sf2 = *(const float4*)(base + 2*(size_t)NP*NS);
    sf3 = *(const float4*)(base + 3*(size_t)NP*NS);
  };

  auto fill = [&](int it2) {
    // feats from staged regs first (frees sf for the frames temps)
    const float* f0 = (const float*)&sf0;
    const float* f1 = (const float*)&sf1;
    const float* f2 = (const float*)&sf2;
    const float* f3 = (const float*)&sf3;
#pragma unroll
    for (int j = 0; j < 4; ++j) {
      uint2 pk;
      pk.x = cvt_pk_bf16(f0[j], f1[j]);
      pk.y = cvt_pk_bf16(f2[j], f3[j]);
      *(uint2*)&xb[swzx(colb + j, 4*chq)] = pk;
    }
    // frames + aligned rows (tid<128: col = (lp,s)); direct loads
    if (tid < 128) {
      const int tile = tile0 + it2;
      const int bb = tile >> 8;
      const int pb = (tile & 255) * 4;
      const int col = tid;
      const int lp = col >> 5, s = col & 31;
      const int p = pb + lp;
      float rel[3], on[3], od[3];
#pragma unroll
      for (int i = 0; i < 3; ++i) {
        rel[i] = inp[(size_t)((bb*NC + 6 + i)*NP + p)*NS + s];
        on[i]  = inp[(size_t)((bb*NC + 3 + i)*NP + p)*NS + s];
        od[i]  = inp[(size_t)((bb*NC + 9 + i)*NP + p)*NS + s];
      }
      // azi = mean over s=1..31 (32-lane butterfly within the s-group)
      float az[3];
#pragma unroll
      for (int i = 0; i < 3; ++i) {
        float sum = rel[i];
#pragma unroll
        for (int m = 1; m < 32; m <<= 1) sum += __shfl_xor(sum, m);
        float v0 = __shfl(rel[i], lane & 32);    // s == 0 lane of this group
        az[i] = (sum - v0) * (1.f/31.f);
      }
      float nr[3];
#pragma unroll
      for (int i = 0; i < 3; ++i) nr[i] = normal[(size_t)(bb*NP + p)*3 + i];
      float nn = sqrtf(nr[0]*nr[0] + nr[1]*nr[1] + nr[2]*nr[2]) + 1e-8f;
      nr[0] /= nn; nr[1] /= nn; nr[2] /= nn;
      float an = sqrtf(az[0]*az[0] + az[1]*az[1] + az[2]*az[2]) + 1e-8f;
      float au[3] = {az[0]/an, az[1]/an, az[2]/an};
      float d = au[0]*nr[0] + au[1]*nr[1] + au[2]*nr[2];
      float xax[3] = {au[0] - d*nr[0], au[1] - d*nr[1], au[2] - d*nr[2]};
      float xn = sqrtf(xax[0]*xax[0] + xax[1]*xax[1] + xax[2]*xax[2]) + 1e-8f;
      xax[0] /= xn; xax[1] /= xn; xax[2] /= xn;
      float yax[3] = {nr[1]*xax[2] - nr[2]*xax[1],
                      nr[2]*xax[0] - nr[0]*xax[2],
                      nr[0]*xax[1] - nr[1]*xax[0]};
      if (s < 3) {    // azi_u -> out channels 0..2
        float o = (s == 0) ? au[0] : ((s == 1) ? au[1] : au[2]);
        out[(size_t)(bb*131 + s)*NP + p] = o;
      }
      float xv[9];
#pragma unroll
      for (int r = 0; r < 3; ++r) {
        const float* Rr = (r == 0) ? xax : ((r == 1) ? yax : nr);
        xv[r]   = Rr[0]*rel[0] + Rr[1]*rel[1] + Rr[2]*rel[2];
        xv[3+r] = Rr[0]*on[0]  + Rr[1]*on[1]  + Rr[2]*on[2];
        xv[6+r] = (Rr[0]*au[0] + Rr[1]*au[1] + Rr[2]*au[2])
                - (Rr[0]*od[0] + Rr[1]*od[1] + Rr[2]*od[2]);
      }
      int4 pk;
      pk.x = (int)cvt_pk_bf16(xv[0], xv[1]);
      pk.y = (int)cvt_pk_bf16(xv[2], xv[3]);
      pk.z = (int)cvt_pk_bf16(xv[4], xv[5]);
      pk.w = (int)cvt_pk_bf16(xv[6], xv[7]);
      *(int4*)&xb[swzx(col, 64)] = pk;
      xb[swzx(col, 72)] = f2bf(xv[8]);
    }
  };

  // ----- prologue -----
  stage(0);
  fill(0);
  stage(1);
  __syncthreads();                       // xb(0) visible

  for (int it = 0; it < TPB; ++it) {
    const int tile = tile0 + it;
    const int bb = tile >> 8;
    const int pb = (tile & 255) * 4;

    // ----- layer 1: h1 = relu(w1 @ x) (bias via ones-row), K=96 -----
    f32x4 acc1[2][4];
#pragma unroll
    for (int mf = 0; mf < 2; ++mf)
#pragma unroll
      for (int nf = 0; nf < 4; ++nf) acc1[mf][nf] = f32x4{0.f,0.f,0.f,0.f};
#pragma unroll
    for (int ks = 0; ks < 3; ++ks) {
      bf16x8 bv[4];
#pragma unroll
      for (int nf = 0; nf < 4; ++nf)
        bv[nf] = *(const bf16x8*)&xb[swzx(64*wc + 16*nf + l15, 32*ks + 8*l4)];
#pragma unroll
      for (int mf = 0; mf < 2; ++mf)
#pragma unroll
        for (int nf = 0; nf < 4; ++nf)
          acc1[mf][nf] = __builtin_amdgcn_mfma_f32_16x16x32_bf16(
              w1f[mf][ks], bv[nf], acc1[mf][nf], 0, 0, 0);
    }
    // h1 -> hb (relu, cvt_pk, b64)
#pragma unroll
    for (int mf = 0; mf < 2; ++mf)
#pragma unroll
      for (int nf = 0; nf < 4; ++nf) {
        const int col = 64*wc + 16*nf + l15;
        const int row0 = 32*wr + 16*mf + 4*l4;
        uint2 pk;
        pk.x = cvt_pk_bf16(fmaxf(acc1[mf][nf][0], 0.f), fmaxf(acc1[mf][nf][1], 0.f));
        pk.y = cvt_pk_bf16(fmaxf(acc1[mf][nf][2], 0.f), fmaxf(acc1[mf][nf][3], 0.f));
        *(uint2*)&hb[swzh(col, row0)] = pk;
      }
    __syncthreads();                     // xb reads done; hb visible

    // x(it+1) fill + stage(it+2) overlap layer-2 compute
    if (it + 1 < TPB) fill(it + 1);
    if (it + 2 < TPB) stage(it + 2);

    // ----- layer 2: h2 = relu(w2 @ h1 + b2), K=128 -----
    f32x4 acc2[2][4];
#pragma unroll
    for (int mf = 0; mf < 2; ++mf)
#pragma unroll
      for (int nf = 0; nf < 4; ++nf) acc2[mf][nf] = f32x4{0.f,0.f,0.f,0.f};
#pragma unroll
    for (int ks = 0; ks < 4; ++ks) {
      bf16x8 bv[4];
#pragma unroll
      for (int nf = 0; nf < 4; ++nf)
        bv[nf] = *(const bf16x8*)&hb[swzh(64*wc + 16*nf + l15, 32*ks + 8*l4)];
#pragma unroll
      for (int mf = 0; mf < 2; ++mf)
#pragma unroll
        for (int nf = 0; nf < 4; ++nf)
          acc2[mf][nf] = __builtin_amdgcn_mfma_f32_16x16x32_bf16(
              w2f[mf][ks], bv[nf], acc2[mf][nf], 0, 0, 0);
    }

    // ----- relu + max-pool over s (DPP butterfly) + store -----
    // wave covers points pb+2*wc (nf 0,1) and pb+2*wc+1 (nf 2,3)
#pragma unroll
    for (int mf = 0; mf < 2; ++mf)
#pragma unroll
      for (int r = 0; r < 4; ++r) {
        float v0 = fmaxf(acc2[mf][0][r], acc2[mf][1][r]);
        float v1 = fmaxf(acc2[mf][2][r], acc2[mf][3][r]);
        v0 = dpp_max16(v0);
        v1 = dpp_max16(v1);
        v0 = fmaxf(v0 + bias2[mf][r], 0.f);
        v1 = fmaxf(v1 + bias2[mf][r], 0.f);
        if (l15 == 0) {
          const int row = 32*wr + 16*mf + 4*l4 + r;
          *(float2*)&out[(size_t)(bb*131 + 3 + row)*NP + pb + 2*wc] = float2{v0, v1};
        }
      }
    __syncthreads();                     // hb reads done; xb(it+1) visible
  }
}

extern "C" void kernel_launch(void* const* d_in, const int* in_sizes, int n_in,
                              void* d_out, int out_size, void* d_ws, size_t ws_size,
                              hipStream_t stream) {
  const float* inp    = (const float*)d_in[0];
  const float* normal = (const float*)d_in[1];
  const float* w1     = (const float*)d_in[2];
  const float* b1     = (const float*)d_in[3];
  const float* w2     = (const float*)d_in[4];
  const float* b2     = (const float*)d_in[5];
  float* out = (float*)d_out;

  // 4096 tiles / TPB=8 -> 512 blocks = 2 per CU (61.4 KB LDS each)
  mlp_kernel<<<dim3(NB*NP/4/TPB), dim3(512), 0, stream>>>(
      inp, w1, b1, w2, b2, normal, out);
}

// Round 10
// 69.257 us; speedup vs baseline: 3.4347x; 3.4347x over previous
//
#include <hip/hip_runtime.h>
#include <hip/hip_bf16.h>

#define NB 16
#define NP 1024
#define NS 32
#define NC 76
#define XSTR 104   // xb k-stride (shorts): 96 used + 8 pad; 16B-multiple
#define HSTR 136   // hb k-stride (shorts): 128 used + 8 pad; 16B-multiple
#define TPB 8      // tiles per block; tile = 4 points; grid = 512 = 2 blocks/CU

typedef __attribute__((ext_vector_type(8))) short bf16x8;
typedef __attribute__((ext_vector_type(4))) float f32x4;

__device__ inline short f2bf(float f) {
  unsigned u = __builtin_bit_cast(unsigned, f);
  u = u + 0x7fffu + ((u >> 16) & 1u);   // RNE
  return (short)(u >> 16);
}
__device__ inline unsigned cvt_pk_bf16(float lo, float hi) {
  unsigned r;
  asm("v_cvt_pk_bf16_f32 %0, %1, %2" : "=v"(r) : "v"(lo), "v"(hi));
  return r;
}
// Swizzle: fold col bits 4..6 (uniform per 16-col fragment window -> read
// bank-pattern untouched) into addr bits 3..5 (16B-granular). Bijective.
__device__ inline int swzx(int col, int k) {
  return (col * XSTR + k) ^ (((col >> 4) & 7) << 3);
}
__device__ inline int swzh(int col, int k) {
  return (col * HSTR + k) ^ (((col >> 4) & 7) << 3);
}
// max across 16-lane groups via DPP butterfly (VALU pipe, no LDS)
__device__ inline float dpp_max16(float v) {
  int x;
  x = __builtin_amdgcn_update_dpp(0, __builtin_bit_cast(int, v), 0xB1, 0xf, 0xf, true);
  v = fmaxf(v, __builtin_bit_cast(float, x));
  x = __builtin_amdgcn_update_dpp(0, __builtin_bit_cast(int, v), 0x4E, 0xf, 0xf, true);
  v = fmaxf(v, __builtin_bit_cast(float, x));
  x = __builtin_amdgcn_update_dpp(0, __builtin_bit_cast(int, v), 0x141, 0xf, 0xf, true);
  v = fmaxf(v, __builtin_bit_cast(float, x));
  x = __builtin_amdgcn_update_dpp(0, __builtin_bit_cast(int, v), 0x140, 0xf, 0xf, true);
  v = fmaxf(v, __builtin_bit_cast(float, x));
  return v;
}

// ---------------- single fused kernel: frames + MLP + pool ----------------
// 512 threads = 8 waves (4 row-stripes x 2 col-halves). Tile = 4 points =
// 128 cols. SINGLE xb / hb buffers (61.4 KB) -> 2 blocks/CU = 16 waves/CU
// when VGPR <= 128 (R8 measured 120 under (512,2) — no hard cap!).
// Loop: L1(t)+h1store | bar | fill(t+1) overlaps L2(t)+pool | bar.
// Frames (azi mean + Gram-Schmidt) in-register inside fill (32-lane shuffle
// reduce per point); azi_u written to out ch 0..2 there.
// xb [col][k]: 0..63 feats(ch12..75); 64..66 R*rel; 67..69 R*o_n; 70..72
// dir_dif; 73 = 1.0 (bias row, static); 74..95 = 0 (static).
__global__ __launch_bounds__(512, 2)   // NO tighter cap: R2/R5/R9 all spilled under one
void mlp_kernel(const float* __restrict__ inp, const float* __restrict__ w1g,
                const float* __restrict__ b1g, const float* __restrict__ w2g,
                const float* __restrict__ b2g, const float* __restrict__ normal,
                float* __restrict__ out) {
  __shared__ short xb[128 * XSTR];   // 26,624 B
  __shared__ short hb[128 * HSTR];   // 34,816 B
  const int tid = threadIdx.x;
  const int lane = tid & 63;
  const int wv = tid >> 6;
  const int wr = wv >> 1;           // row-stripe 0..3 -> rows 32*wr..
  const int wc = wv & 1;            // col-half 0..1 -> cols 64*wc..
  const int l15 = lane & 15;
  const int l4 = lane >> 4;         // 0..3

  const int tile0 = blockIdx.x * TPB;

  // fill-phase thread map (feats)
  const int s4  = tid & 7;          // s quad
  const int flp = (tid >> 3) & 3;   // point within tile
  const int chq = tid >> 5;         // channel quad 0..15 -> k = 4*chq
  const int colb = flp*32 + 4*s4;

  // ----- weight fragments (rows 32*wr+16*mf+l15); b1 folded at kk=73 -----
  bf16x8 w1f[2][3];
#pragma unroll
  for (int mf = 0; mf < 2; ++mf)
#pragma unroll
    for (int ks = 0; ks < 3; ++ks) {
      bf16x8 a;
#pragma unroll
      for (int j = 0; j < 8; ++j) {
        int row = 32*wr + 16*mf + l15;
        int kk = 32*ks + 8*l4 + j;
        float v = 0.f;
        if (kk < 73) {
          int c = (kk < 64) ? (kk + 3) : ((kk < 67) ? (kk - 64) : kk);
          v = w1g[row*73 + c];
        } else if (kk == 73) {
          v = b1g[row];
        }
        a[j] = f2bf(v);
      }
      w1f[mf][ks] = a;
    }
  bf16x8 w2f[2][4];
#pragma unroll
  for (int mf = 0; mf < 2; ++mf)
#pragma unroll
    for (int ks = 0; ks < 4; ++ks) {
      bf16x8 a;
#pragma unroll
      for (int j = 0; j < 8; ++j) {
        int row = 32*wr + 16*mf + l15;
        int kk = 32*ks + 8*l4 + j;
        a[j] = f2bf(w2g[row*128 + kk]);
      }
      w2f[mf][ks] = a;
    }
  float bias2[2][4];
#pragma unroll
  for (int mf = 0; mf < 2; ++mf)
#pragma unroll
    for (int r = 0; r < 4; ++r)
      bias2[mf][r] = b2g[32*wr + 16*mf + 4*l4 + r];

  // static pad region of xb: k=73 -> 1.0, (73,96) -> 0
  for (int i = tid; i < 128*23; i += 512) {
    int col = i / 23;
    int k = 73 + (i - col*23);
    xb[swzx(col, k)] = (k == 73) ? (short)0x3F80 : (short)0;
  }

  // ----- feat staging registers (next tile); dead before frames block -----
  float4 sf0, sf1, sf2, sf3;
  auto stage = [&](int it2) {
    const int tile = tile0 + it2;
    const int bb = tile >> 8;
    const int pb = (tile & 255) * 4;
    const float* base = inp + ((size_t)((bb*NC + 12 + 4*chq)*NP) + pb + flp)*NS + 4*s4;
    sf0 = *(const float4*)(base + 0*(size_t)NP*NS);
    sf1 = *(const float4*)(base + 1*(size_t)NP*NS);
    sf2 = *(const float4*)(base + 2*(size_t)NP*NS);
    sf3 = *(const float4*)(base + 3*(size_t)NP*NS);
  };

  auto fill = [&](int it2) {
    // feats from staged regs first (frees sf for the frames temps)
    const float* f0 = (const float*)&sf0;
    const float* f1 = (const float*)&sf1;
    const float* f2 = (const float*)&sf2;
    const float* f3 = (const float*)&sf3;
#pragma unroll
    for (int j = 0; j < 4; ++j) {
      uint2 pk;
      pk.x = cvt_pk_bf16(f0[j], f1[j]);
      pk.y = cvt_pk_bf16(f2[j], f3[j]);
      *(uint2*)&xb[swzx(colb + j, 4*chq)] = pk;
    }
    // frames + aligned rows (tid<128: col = (lp,s)); direct loads
    if (tid < 128) {
      const int tile = tile0 + it2;
      const int bb = tile >> 8;
      const int pb = (tile & 255) * 4;
      const int col = tid;
      const int lp = col >> 5, s = col & 31;
      const int p = pb + lp;
      float rel[3], on[3], od[3];
#pragma unroll
      for (int i = 0; i < 3; ++i) {
        rel[i] = inp[(size_t)((bb*NC + 6 + i)*NP + p)*NS + s];
        on[i]  = inp[(size_t)((bb*NC + 3 + i)*NP + p)*NS + s];
        od[i]  = inp[(size_t)((bb*NC + 9 + i)*NP + p)*NS + s];
      }
      // azi = mean over s=1..31 (32-lane butterfly within the s-group)
      float az[3];
#pragma unroll
      for (int i = 0; i < 3; ++i) {
        float sum = rel[i];
#pragma unroll
        for (int m = 1; m < 32; m <<= 1) sum += __shfl_xor(sum, m);
        float v0 = __shfl(rel[i], lane & 32);    // s == 0 lane of this group
        az[i] = (sum - v0) * (1.f/31.f);
      }
      float nr[3];
#pragma unroll
      for (int i = 0; i < 3; ++i) nr[i] = normal[(size_t)(bb*NP + p)*3 + i];
      float nn = sqrtf(nr[0]*nr[0] + nr[1]*nr[1] + nr[2]*nr[2]) + 1e-8f;
      nr[0] /= nn; nr[1] /= nn; nr[2] /= nn;
      float an = sqrtf(az[0]*az[0] + az[1]*az[1] + az[2]*az[2]) + 1e-8f;
      float au[3] = {az[0]/an, az[1]/an, az[2]/an};
      float d = au[0]*nr[0] + au[1]*nr[1] + au[2]*nr[2];
      float xax[3] = {au[0] - d*nr[0], au[1] - d*nr[1], au[2] - d*nr[2]};
      float xn = sqrtf(xax[0]*xax[0] + xax[1]*xax[1] + xax[2]*xax[2]) + 1e-8f;
      xax[0] /= xn; xax[1] /= xn; xax[2] /= xn;
      float yax[3] = {nr[1]*xax[2] - nr[2]*xax[1],
                      nr[2]*xax[0] - nr[0]*xax[2],
                      nr[0]*xax[1] - nr[1]*xax[0]};
      if (s < 3) {    // azi_u -> out channels 0..2
        float o = (s == 0) ? au[0] : ((s == 1) ? au[1] : au[2]);
        out[(size_t)(bb*131 + s)*NP + p] = o;
      }
      float xv[9];
#pragma unroll
      for (int r = 0; r < 3; ++r) {
        const float* Rr = (r == 0) ? xax : ((r == 1) ? yax : nr);
        xv[r]   = Rr[0]*rel[0] + Rr[1]*rel[1] + Rr[2]*rel[2];
        xv[3+r] = Rr[0]*on[0]  + Rr[1]*on[1]  + Rr[2]*on[2];
        xv[6+r] = (Rr[0]*au[0] + Rr[1]*au[1] + Rr[2]*au[2])
                - (Rr[0]*od[0] + Rr[1]*od[1] + Rr[2]*od[2]);
      }
      int4 pk;
      pk.x = (int)cvt_pk_bf16(xv[0], xv[1]);
      pk.y = (int)cvt_pk_bf16(xv[2], xv[3]);
      pk.z = (int)cvt_pk_bf16(xv[4], xv[5]);
      pk.w = (int)cvt_pk_bf16(xv[6], xv[7]);
      *(int4*)&xb[swzx(col, 64)] = pk;
      xb[swzx(col, 72)] = f2bf(xv[8]);
    }
  };

  // ----- prologue -----
  stage(0);
  fill(0);
  stage(1);
  __syncthreads();                       // xb(0) visible

  for (int it = 0; it < TPB; ++it) {
    const int tile = tile0 + it;
    const int bb = tile >> 8;
    const int pb = (tile & 255) * 4;

    // ----- layer 1: h1 = relu(w1 @ x) (bias via ones-row), K=96 -----
    f32x4 acc1[2][4];
#pragma unroll
    for (int mf = 0; mf < 2; ++mf)
#pragma unroll
      for (int nf = 0; nf < 4; ++nf) acc1[mf][nf] = f32x4{0.f,0.f,0.f,0.f};
#pragma unroll
    for (int ks = 0; ks < 3; ++ks) {
      bf16x8 bv[4];
#pragma unroll
      for (int nf = 0; nf < 4; ++nf)
        bv[nf] = *(const bf16x8*)&xb[swzx(64*wc + 16*nf + l15, 32*ks + 8*l4)];
#pragma unroll
      for (int mf = 0; mf < 2; ++mf)
#pragma unroll
        for (int nf = 0; nf < 4; ++nf)
          acc1[mf][nf] = __builtin_amdgcn_mfma_f32_16x16x32_bf16(
              w1f[mf][ks], bv[nf], acc1[mf][nf], 0, 0, 0);
    }
    // h1 -> hb (relu, cvt_pk, b64)
#pragma unroll
    for (int mf = 0; mf < 2; ++mf)
#pragma unroll
      for (int nf = 0; nf < 4; ++nf) {
        const int col = 64*wc + 16*nf + l15;
        const int row0 = 32*wr + 16*mf + 4*l4;
        uint2 pk;
        pk.x = cvt_pk_bf16(fmaxf(acc1[mf][nf][0], 0.f), fmaxf(acc1[mf][nf][1], 0.f));
        pk.y = cvt_pk_bf16(fmaxf(acc1[mf][nf][2], 0.f), fmaxf(acc1[mf][nf][3], 0.f));
        *(uint2*)&hb[swzh(col, row0)] = pk;
      }
    __syncthreads();                     // xb reads done; hb visible

    // x(it+1) fill + stage(it+2) overlap layer-2 compute
    if (it + 1 < TPB) fill(it + 1);
    if (it + 2 < TPB) stage(it + 2);

    // ----- layer 2: h2 = relu(w2 @ h1 + b2), K=128 -----
    f32x4 acc2[2][4];
#pragma unroll
    for (int mf = 0; mf < 2; ++mf)
#pragma unroll
      for (int nf = 0; nf < 4; ++nf) acc2[mf][nf] = f32x4{0.f,0.f,0.f,0.f};
#pragma unroll
    for (int ks = 0; ks < 4; ++ks) {
      bf16x8 bv[4];
#pragma unroll
      for (int nf = 0; nf < 4; ++nf)
        bv[nf] = *(const bf16x8*)&hb[swzh(64*wc + 16*nf + l15, 32*ks + 8*l4)];
#pragma unroll
      for (int mf = 0; mf < 2; ++mf)
#pragma unroll
        for (int nf = 0; nf < 4; ++nf)
          acc2[mf][nf] = __builtin_amdgcn_mfma_f32_16x16x32_bf16(
              w2f[mf][ks], bv[nf], acc2[mf][nf], 0, 0, 0);
    }

    // ----- relu + max-pool over s (DPP butterfly) + store -----
    // wave covers points pb+2*wc (nf 0,1) and pb+2*wc+1 (nf 2,3)
#pragma unroll
    for (int mf = 0; mf < 2; ++mf)
#pragma unroll
      for (int r = 0; r < 4; ++r) {
        float v0 = fmaxf(acc2[mf][0][r], acc2[mf][1][r]);
        float v1 = fmaxf(acc2[mf][2][r], acc2[mf][3][r]);
        v0 = dpp_max16(v0);
        v1 = dpp_max16(v1);
        v0 = fmaxf(v0 + bias2[mf][r], 0.f);
        v1 = fmaxf(v1 + bias2[mf][r], 0.f);
        if (l15 == 0) {
          const int row = 32*wr + 16*mf + 4*l4 + r;
          *(float2*)&out[(size_t)(bb*131 + 3 + row)*NP + pb + 2*wc] = float2{v0, v1};
        }
      }
    __syncthreads();                     // hb reads done; xb(it+1) visible
  }
}

extern "C" void kernel_launch(void* const* d_in, const int* in_sizes, int n_in,
                              void* d_out, int out_size, void* d_ws, size_t ws_size,
                              hipStream_t stream) {
  const float* inp    = (const float*)d_in[0];
  const float* normal = (const float*)d_in[1];
  const float* w1     = (const float*)d_in[2];
  const float* b1     = (const float*)d_in[3];
  const float* w2     = (const float*)d_in[4];
  const float* b2     = (const float*)d_in[5];
  float* out = (float*)d_out;

  // 4096 tiles / TPB=8 -> 512 blocks; 61.4 KB LDS -> 2 blocks/CU if VGPR<=128
  mlp_kernel<<<dim3(NB*NP/4/TPB), dim3(512), 0, stream>>>(
      inp, w1, b1, w2, b2, normal, out);
}